// Round 1
// 367.592 us; speedup vs baseline: 1.1256x; 1.1256x over previous
//
#include <hip/hip_runtime.h>
#include <hip/hip_bf16.h>
#include <math.h>

#define NNODES 4096
#define NCOLS  96          // B*T
#define NROWS  12288       // K*NNODES
#define BM     48          // rows per block (256 blocks exactly)
#define BK     64          // k per LDS stage

typedef __attribute__((ext_vector_type(8))) short short8;
typedef __attribute__((ext_vector_type(4))) float float4v;

// ---------------------------------------------------------------------------
// Dtype probe: flag[0]=1 => inputs fp32, 0 => bf16. (Validated: fp32 on this
// harness — earlier rounds passed through the fp32 path.)
// ---------------------------------------------------------------------------
__global__ void probe_dtype(const unsigned int* __restrict__ aw, int* __restrict__ flag) {
    int tid = threadIdx.x;
    unsigned w = aw[tid];
    unsigned e = (w >> 7) & 0xffu;
    bool insane = (e >= 0xC0u) || (e <= 0x30u);
    unsigned long long m = __ballot(insane);
    if (tid == 0) flag[0] = (__popcll(m) >= 16) ? 1 : 0;
}

__device__ __forceinline__ float ldf(const void* p, size_t i, int isf32) {
    return isf32 ? ((const float*)p)[i]
                 : __bfloat162float(((const __hip_bfloat16*)p)[i]);
}

__device__ __forceinline__ void ld8(float* d, const void* p, size_t e, int isf32) {
    if (isf32) {
        const float4* s = (const float4*)((const float*)p + e);
        float4 f0 = s[0], f1 = s[1];
        d[0] = f0.x; d[1] = f0.y; d[2] = f0.z; d[3] = f0.w;
        d[4] = f1.x; d[5] = f1.y; d[6] = f1.z; d[7] = f1.w;
    } else {
        const __hip_bfloat16* s = (const __hip_bfloat16*)p + e;
#pragma unroll
        for (int j = 0; j < 8; j++) d[j] = __bfloat162float(s[j]);
    }
}

// pack 8 fp32 -> short8 of bf16 (RNE via __float2bfloat16)
__device__ __forceinline__ short8 cvt8(float4 a, float4 b) {
    union { short8 v; __hip_bfloat16 h[8]; } u;
    u.h[0] = __float2bfloat16(a.x); u.h[1] = __float2bfloat16(a.y);
    u.h[2] = __float2bfloat16(a.z); u.h[3] = __float2bfloat16(a.w);
    u.h[4] = __float2bfloat16(b.x); u.h[5] = __float2bfloat16(b.y);
    u.h[6] = __float2bfloat16(b.z); u.h[7] = __float2bfloat16(b.w);
    return u.v;
}

// ---------------------------------------------------------------------------
// Kernel 1: y = adj(12288x4096) @ X^T (X = x as 96x4096), bf16 MFMA 16x16x32.
// Grid 256 blocks x 192 thr (3 waves) -> 100% CU coverage. Tile 48x96, BK=64.
// LDS stored as 16B chunks (8 bf16) with XOR swizzle: row r, k-chunk c lives
// at slot r*8 + (c ^ (r&7))  -> conflict-free ds_read_b128 frag reads
// (linear 128B rows would be 16-way; old +8 pad was 8-way).
// Double-buffered LDS: ONE barrier per K-step; register prefetch 1 iter ahead.
// Output: yws[row*96 + col] fp32, row = k*4096+n, col = b*12+t.
// C/D mapping P0 (HW-validated): col=lane&15, row=(lane>>4)*4+reg.
// ---------------------------------------------------------------------------
__global__ __launch_bounds__(192) void gemm_y(
    const void* __restrict__ adjv, const void* __restrict__ xv,
    float* __restrict__ yws, const int* __restrict__ flag)
{
    __shared__ __align__(16) short8 As[2][BM * 8];   // 48 rows x 8 chunks
    __shared__ __align__(16) short8 Xs[2][96 * 8];   // 96 rows x 8 chunks

    const int tid = threadIdx.x;
    const int isf32 = flag[0];
    const size_t row0 = (size_t)blockIdx.x * BM;

    const int wv = tid >> 6;           // wave 0..2 -> row-tile
    const int ln = tid & 63;
    const int fr = ln & 15;
    const int fq = ln >> 4;

    float4v acc[6];
#pragma unroll
    for (int i = 0; i < 6; i++) acc[i] = (float4v){0.f, 0.f, 0.f, 0.f};

    // staging chunk assignment: A = 48*8 = 384 chunks (2/thr), X = 96*8 = 768 (4/thr)
    int arow[2], acol[2], aslot[2];
#pragma unroll
    for (int s = 0; s < 2; s++) {
        int g = tid + s * 192;
        arow[s] = g >> 3; acol[s] = (g & 7) * 8;
        aslot[s] = (g >> 3) * 8 + ((g & 7) ^ ((g >> 3) & 7));
    }
    int xrow[4], xcol[4], xslot[4];
#pragma unroll
    for (int s = 0; s < 4; s++) {
        int g = tid + s * 192;
        xrow[s] = g >> 3; xcol[s] = (g & 7) * 8;
        xslot[s] = (g >> 3) * 8 + ((g & 7) ^ ((g >> 3) & 7));
    }

    if (isf32) {
        const float* adjf = (const float*)adjv;
        const float* xf   = (const float*)xv;

        float4 pa[2][2], px[4][2];
        // preload chunk kk=0
#pragma unroll
        for (int s = 0; s < 2; s++) {
            const float* p = adjf + (row0 + arow[s]) * NNODES + acol[s];
            pa[s][0] = *(const float4*)p; pa[s][1] = *(const float4*)(p + 4);
        }
#pragma unroll
        for (int s = 0; s < 4; s++) {
            const float* p = xf + (size_t)xrow[s] * NNODES + xcol[s];
            px[s][0] = *(const float4*)p; px[s][1] = *(const float4*)(p + 4);
        }

        int buf = 0;
        for (int kk = 0; kk < NNODES; kk += BK) {
            // write prefetched regs (data for kk) into buf
#pragma unroll
            for (int s = 0; s < 2; s++) As[buf][aslot[s]] = cvt8(pa[s][0], pa[s][1]);
#pragma unroll
            for (int s = 0; s < 4; s++) Xs[buf][xslot[s]] = cvt8(px[s][0], px[s][1]);
            // issue next-tile loads (covered by this iter's MFMA + barrier)
            if (kk + BK < NNODES) {
                const int kn = kk + BK;
#pragma unroll
                for (int s = 0; s < 2; s++) {
                    const float* p = adjf + (row0 + arow[s]) * NNODES + kn + acol[s];
                    pa[s][0] = *(const float4*)p; pa[s][1] = *(const float4*)(p + 4);
                }
#pragma unroll
                for (int s = 0; s < 4; s++) {
                    const float* p = xf + (size_t)xrow[s] * NNODES + kn + xcol[s];
                    px[s][0] = *(const float4*)p; px[s][1] = *(const float4*)(p + 4);
                }
            }
            __syncthreads();   // buf ready for all waves; prev buf free to overwrite next iter
#pragma unroll
            for (int kq = 0; kq < 2; kq++) {
                short8 a = As[buf][(wv * 16 + fr) * 8 + ((kq * 4 + fq) ^ (fr & 7))];
#pragma unroll
                for (int ct = 0; ct < 6; ct++) {
                    short8 bfr = Xs[buf][(ct * 16 + fr) * 8 + ((kq * 4 + fq) ^ (fr & 7))];
                    acc[ct] = __builtin_amdgcn_mfma_f32_16x16x32_bf16(a, bfr, acc[ct], 0, 0, 0);
                }
            }
            buf ^= 1;
        }
    } else {
        // bf16 input path (insurance): chunks are 16B uint4, no conversion
        const __hip_bfloat16* adjb = (const __hip_bfloat16*)adjv;
        const __hip_bfloat16* xb   = (const __hip_bfloat16*)xv;

        uint4 pa[2], px[4];
#pragma unroll
        for (int s = 0; s < 2; s++)
            pa[s] = *(const uint4*)(adjb + (row0 + arow[s]) * NNODES + acol[s]);
#pragma unroll
        for (int s = 0; s < 4; s++)
            px[s] = *(const uint4*)(xb + (size_t)xrow[s] * NNODES + xcol[s]);

        int buf = 0;
        for (int kk = 0; kk < NNODES; kk += BK) {
#pragma unroll
            for (int s = 0; s < 2; s++) *(uint4*)&As[buf][aslot[s]] = pa[s];
#pragma unroll
            for (int s = 0; s < 4; s++) *(uint4*)&Xs[buf][xslot[s]] = px[s];
            if (kk + BK < NNODES) {
                const int kn = kk + BK;
#pragma unroll
                for (int s = 0; s < 2; s++)
                    pa[s] = *(const uint4*)(adjb + (row0 + arow[s]) * NNODES + kn + acol[s]);
#pragma unroll
                for (int s = 0; s < 4; s++)
                    px[s] = *(const uint4*)(xb + (size_t)xrow[s] * NNODES + kn + xcol[s]);
            }
            __syncthreads();
#pragma unroll
            for (int kq = 0; kq < 2; kq++) {
                short8 a = As[buf][(wv * 16 + fr) * 8 + ((kq * 4 + fq) ^ (fr & 7))];
#pragma unroll
                for (int ct = 0; ct < 6; ct++) {
                    short8 bfr = Xs[buf][(ct * 16 + fr) * 8 + ((kq * 4 + fq) ^ (fr & 7))];
                    acc[ct] = __builtin_amdgcn_mfma_f32_16x16x32_bf16(a, bfr, acc[ct], 0, 0, 0);
                }
            }
            buf ^= 1;
        }
    }

    // store: P0 mapping
#pragma unroll
    for (int ct = 0; ct < 6; ct++)
#pragma unroll
        for (int rg = 0; rg < 4; rg++) {
            size_t r = row0 + wv * 16 + fq * 4 + rg;
            yws[r * NCOLS + ct * 16 + fr] = acc[ct][rg];
        }
}

// ---------------------------------------------------------------------------
// Kernel 2: epilogue. 4 lanes (a quad) per (b,n): each lane owns 3 t's of the
// cheb/sgc sum, quad-reduced via shfl_xor; GLU o-range split across the quad.
// 512 blocks x 256 thr = 2048 waves = 2 waves/SIMD (was 0.5).
// yws layout [k*4096+n][b*12+t].
// ---------------------------------------------------------------------------
__global__ __launch_bounds__(256) void epilogue_kernel(
    const void* __restrict__ xv, const float* __restrict__ yws,
    const void* __restrict__ chebv, const void* __restrict__ gcnwv,
    const void* __restrict__ gcnbv, const void* __restrict__ g1wv,
    const void* __restrict__ g1bv, const void* __restrict__ g2wv,
    const void* __restrict__ g2bv,
    float* __restrict__ out, const int* __restrict__ flag)
{
    __shared__ float gwL[9216];   // [t][j*12+o]
    __shared__ float cwL[192];    // [j*3+k]
    __shared__ float w1L[216];    // [o*18 + c*3 + kh]  (kw=1 tap)
    __shared__ float w2L[216];
    __shared__ float wbL[36];

    const int tid = threadIdx.x;
    const int isf32 = flag[0];

    for (int i = tid; i < 9216; i += 256) {
        int o = i / 768, t = (i / 64) % 12, j = i % 64;   // gcn_w flat (o,t,0,j)
        gwL[t * 768 + j * 12 + o] = ldf(gcnwv, i, isf32);
    }
    if (tid < 192) cwL[tid] = ldf(chebv, tid, isf32);
    if (tid < 216) {
        w1L[tid] = ldf(g1wv, (size_t)tid * 3 + 1, isf32);
        w2L[tid] = ldf(g2wv, (size_t)tid * 3 + 1, isf32);
    }
    if (tid < 12) {
        wbL[tid]      = ldf(gcnbv, tid, isf32);
        wbL[12 + tid] = ldf(g1bv, tid, isf32);
        wbL[24 + tid] = ldf(g2bv, tid, isf32);
    }
    __syncthreads();

    const int gid = blockIdx.x * 256 + tid;   // 0..131071
    const int pr  = gid >> 2;                 // (b,n) pair 0..32767
    const int tq  = gid & 3;                  // t-quarter 0..3
    const int b = pr >> 12;
    const int n = pr & (NNODES - 1);

    // y values for this lane's 3 t's
    float yk[3][3];
#pragma unroll
    for (int k = 0; k < 3; k++) {
        const float* yp = yws + ((size_t)(k * NNODES + n)) * NCOLS + b * 12 + tq * 3;
        yk[k][0] = yp[0]; yk[k][1] = yp[1]; yk[k][2] = yp[2];
    }

    // ---- cheb -> relu -> partial sgc over 3 t's ----
    float sg[12];
#pragma unroll
    for (int o = 0; o < 12; o++) sg[o] = 0.f;
#pragma unroll
    for (int i = 0; i < 3; i++) {
        const float y0 = yk[0][i], y1 = yk[1][i], y2 = yk[2][i];
        const float* gwt = gwL + (tq * 3 + i) * 768;
#pragma unroll 4
        for (int j = 0; j < 64; j++) {
            float h = y0 * cwL[j * 3] + y1 * cwL[j * 3 + 1] + y2 * cwL[j * 3 + 2];
            h = fmaxf(h, 0.f);
#pragma unroll
            for (int o = 0; o < 12; o++) sg[o] += h * gwt[j * 12 + o];
        }
    }
    // quad reduction: all 4 lanes end with the full t-sum
#pragma unroll
    for (int o = 0; o < 12; o++) {
        sg[o] += __shfl_xor(sg[o], 1);
        sg[o] += __shfl_xor(sg[o], 2);
    }

    // ---- GLU (dilated conv taps n-2, n, n+2; only kw=1 alive); this lane
    // handles o = tq*3 .. tq*3+2 ----
    float xa[18], xg[18];
#pragma unroll
    for (int c = 0; c < 6; c++)
#pragma unroll
        for (int kh = 0; kh < 3; kh++) {
            int m = n + 2 * kh - 2;
            bool ok = ((unsigned)m < (unsigned)NNODES);
            xa[c * 3 + kh] = ok ? ldf(xv, ((size_t)(b * 12 + c)) * NNODES + m, isf32) : 0.f;
            xg[c * 3 + kh] = ok ? ldf(xv, ((size_t)(b * 12 + c + 6)) * NNODES + m, isf32) : 0.f;
        }

#pragma unroll
    for (int i = 0; i < 3; i++) {
        const int o = tq * 3 + i;
        float av = wbL[12 + o], gv = wbL[24 + o];
#pragma unroll
        for (int q = 0; q < 18; q++) {
            av += xa[q] * w1L[o * 18 + q];
            gv += xg[q] * w2L[o * 18 + q];
        }
        float s = 1.f / (1.f + expf(-gv));
        out[((size_t)(b * 12 + o)) * NNODES + n] = av * s + sg[o] + wbL[o];
    }
}

// ---------------------------------------------------------------------------
// Fallback single kernel (only if ws too small): round-5 verified path.
// ---------------------------------------------------------------------------
__global__ __launch_bounds__(64) void fused_simple(
    const void* __restrict__ xv, const void* __restrict__ adjv,
    const void* __restrict__ chebv, const void* __restrict__ gcnwv,
    const void* __restrict__ gcnbv, const void* __restrict__ g1wv,
    const void* __restrict__ g1bv, const void* __restrict__ g2wv,
    const void* __restrict__ g2bv,
    float* __restrict__ out, const int* __restrict__ flag)
{
    __shared__ float gwL[9216];
    __shared__ float cwL[192];
    __shared__ float w1L[216];
    __shared__ float w2L[216];
    __shared__ float wbL[36];

    const int tid = threadIdx.x;
    const int isf32 = flag[0];

    for (int i = tid; i < 9216; i += 64) {
        int o = i / 768, t = (i / 64) % 12, j = i % 64;
        gwL[t * 768 + j * 12 + o] = ldf(gcnwv, i, isf32);
    }
    for (int i = tid; i < 192; i += 64) cwL[i] = ldf(chebv, i, isf32);
    for (int i = tid; i < 216; i += 64) {
        w1L[i] = ldf(g1wv, (size_t)i * 3 + 1, isf32);
        w2L[i] = ldf(g2wv, (size_t)i * 3 + 1, isf32);
    }
    if (tid < 12) {
        wbL[tid]      = ldf(gcnbv, tid, isf32);
        wbL[12 + tid] = ldf(g1bv, tid, isf32);
        wbL[24 + tid] = ldf(g2bv, tid, isf32);
    }
    __syncthreads();

    const int g = blockIdx.x * 64 + tid;
    const int b = g >> 12;
    const int n = g & (NNODES - 1);

    float y[3][12];
#pragma unroll
    for (int k = 0; k < 3; k++)
#pragma unroll
        for (int t = 0; t < 12; t++) y[k][t] = 0.f;

    for (int m0 = 0; m0 < NNODES; m0 += 8) {
        float a0[8], a1[8], a2[8];
        ld8(a0, adjv, ((size_t)(0 * NNODES + n)) * NNODES + m0, isf32);
        ld8(a1, adjv, ((size_t)(1 * NNODES + n)) * NNODES + m0, isf32);
        ld8(a2, adjv, ((size_t)(2 * NNODES + n)) * NNODES + m0, isf32);
#pragma unroll
        for (int t = 0; t < 12; t++) {
            float x8[8];
            ld8(x8, xv, ((size_t)(b * 12 + t)) * NNODES + m0, isf32);
#pragma unroll
            for (int j = 0; j < 8; j++) {
                y[0][t] += a0[j] * x8[j];
                y[1][t] += a1[j] * x8[j];
                y[2][t] += a2[j] * x8[j];
            }
        }
    }

    float sg[12];
#pragma unroll
    for (int o = 0; o < 12; o++) sg[o] = wbL[o];
    for (int t = 0; t < 12; t++) {
        const float y0 = y[0][t], y1 = y[1][t], y2 = y[2][t];
        const float* gwt = gwL + t * 768;
#pragma unroll 4
        for (int j = 0; j < 64; j++) {
            float h = y0 * cwL[j * 3] + y1 * cwL[j * 3 + 1] + y2 * cwL[j * 3 + 2];
            h = fmaxf(h, 0.f);
#pragma unroll
            for (int o = 0; o < 12; o++) sg[o] += h * gwt[j * 12 + o];
        }
    }

    float xa[18], xg[18];
#pragma unroll
    for (int c = 0; c < 6; c++)
#pragma unroll
        for (int kh = 0; kh < 3; kh++) {
            int m = n + 2 * kh - 2;
            bool ok = ((unsigned)m < (unsigned)NNODES);
            xa[c * 3 + kh] = ok ? ldf(xv, ((size_t)(b * 12 + c)) * NNODES + m, isf32) : 0.f;
            xg[c * 3 + kh] = ok ? ldf(xv, ((size_t)(b * 12 + c + 6)) * NNODES + m, isf32) : 0.f;
        }

#pragma unroll
    for (int o = 0; o < 12; o++) {
        float av = wbL[12 + o], gv = wbL[24 + o];
#pragma unroll
        for (int i = 0; i < 18; i++) {
            av += xa[i] * w1L[o * 18 + i];
            gv += xg[i] * w2L[o * 18 + i];
        }
        float s = 1.f / (1.f + expf(-gv));
        out[((size_t)(b * 12 + o)) * NNODES + n] = av * s + sg[o];
    }
}

// ---------------------------------------------------------------------------
extern "C" void kernel_launch(void* const* d_in, const int* in_sizes, int n_in,
                              void* d_out, int out_size, void* d_ws, size_t ws_size,
                              hipStream_t stream)
{
    int* flag = (int*)d_ws;                       // 64 B reserved
    float* yws = (float*)((char*)d_ws + 64);      // 12288*96 floats = 4.72 MB
    const size_t need = 64 + (size_t)NROWS * NCOLS * 4;

    hipLaunchKernelGGL(probe_dtype, dim3(1), dim3(64), 0, stream,
                       (const unsigned int*)d_in[1], flag);

    if (ws_size >= need) {
        hipLaunchKernelGGL(gemm_y, dim3(256), dim3(192), 0, stream,
                           d_in[1], d_in[0], yws, flag);
        hipLaunchKernelGGL(epilogue_kernel, dim3(512), dim3(256), 0, stream,
                           d_in[0], yws, d_in[2], d_in[3], d_in[4],
                           d_in[5], d_in[6], d_in[7], d_in[8],
                           (float*)d_out, flag);
    } else {
        hipLaunchKernelGGL(fused_simple, dim3(512), dim3(64), 0, stream,
                           d_in[0], d_in[1], d_in[2], d_in[3], d_in[4],
                           d_in[5], d_in[6], d_in[7], d_in[8],
                           (float*)d_out, flag);
    }
}